// Round 4
// baseline (357.532 us; speedup 1.0000x reference)
//
#include <hip/hip_runtime.h>
#include <math.h>

// ---------------- problem constants ----------------
constexpr int BN = 65536;   // batch
constexpr int DK = 512;     // feature dim
constexpr int CN = 50;      // classes
constexpr int FILTK = 10;   // per-class top-K
constexpr int MB = 64;      // rows per GEMM block (64 -> 1024 blocks -> 4/CU)
constexpr int SELB = 64;    // blocks per selection pass
constexpr int CAP = 6144;   // per-class LDS entry cap in tail
constexpr int ASTR = 132;   // padded LDS row stride (floats): 2-way bank aliasing only

typedef __attribute__((ext_vector_type(8))) short short8;
typedef __attribute__((ext_vector_type(4))) float f4;

// ---------------- workspace layout (u32 words) ----------------
constexpr int W_SC     = 0;                  // 64 (Scalars)
constexpr int W_H1     = 64;                 // 2048
constexpr int W_H2LO   = 2112;               // 2048
constexpr int W_H2HI   = 4160;               // 2048
constexpr int W_H3LO   = 6208;               // 1024
constexpr int W_H3HI   = 7232;               // 1024
constexpr int ZERO_WORDS = 8256;             // zeroed every call by init_kernel
constexpr int W_WFH    = 8256;               // W frags hi: 32768 ushort = 16384 words
constexpr int W_WFL    = W_WFH + 16384;
constexpr int W_CFH    = W_WFL + 16384;      // centroid frags hi
constexpr int W_CFL    = W_CFH + 16384;
constexpr int W_ENT    = W_CFL + 16384;      // BN
constexpr int W_PMAX   = W_ENT  + BN;
constexpr int W_YHAT   = W_PMAX + BN;
constexpr int W_CONS   = W_YHAT + BN;
constexpr int W_NORM   = W_CONS + BN;
constexpr int W_LAB0   = W_NORM + BN;        // 64
constexpr int W_ENT0   = W_LAB0 + 64;
constexpr int W_CONF0  = W_ENT0 + 64;
constexpr int W_WNORM  = W_CONF0 + 64;
constexpr int LE_CAP   = BN + 64;
constexpr int W_LECLS  = W_WNORM + 64;
constexpr int W_LEENT  = W_LECLS  + LE_CAP;
constexpr int W_LECONF = W_LEENT  + LE_CAP;
constexpr int W_LEORD  = W_LECONF + LE_CAP;
constexpr int W_LESRC  = W_LEORD  + LE_CAP;

struct Scalars {
    float    sum_ent;
    float    mean;
    float    conf_thr;
    float    frac;
    int      klo;
    int      khi;
    unsigned prefix_lo;
    unsigned rank_lo;
    unsigned prefix_hi;
    unsigned rank_hi;
    float    thr;
    unsigned cnt;
    unsigned done1, done2, done3;
};

// monotone float<->u32 key
__device__ __forceinline__ unsigned fkey(float f) {
    unsigned u = __float_as_uint(f);
    return (u & 0x80000000u) ? ~u : (u | 0x80000000u);
}
__device__ __forceinline__ float funkey(unsigned u) {
    return (u & 0x80000000u) ? __uint_as_float(u & 0x7fffffffu) : __uint_as_float(~u);
}

// bf16 split helpers (RNE)
__device__ __forceinline__ short bf16h(float x) {
    unsigned u = __float_as_uint(x);
    return (short)((u + 0x7fffu + ((u >> 16) & 1u)) >> 16);
}
__device__ __forceinline__ float bf16tof(short h) {
    return __uint_as_float(((unsigned)(unsigned short)h) << 16);
}
__device__ __forceinline__ void cvt8(const float* a, short8& h, short8& l) {
    #pragma unroll
    for (int j = 0; j < 8; j++) {
        short hh = bf16h(a[j]);
        h[j] = hh;
        l[j] = bf16h(a[j] - bf16tof(hh));
    }
}
// frag element index: [ks][ntile][lane=(n&15)+16q][j]
__device__ __forceinline__ int fragidx(int ks, int n, int q, int j) {
    return ks * 2048 + (n >> 4) * 512 + ((n & 15) + 16 * q) * 8 + j;
}

// ---------------- init: W frag rows + warmup stats + zero ----------------
__global__ void init_kernel(const float* __restrict__ W, const float* __restrict__ bias,
                            int* __restrict__ lab0, float* __restrict__ ent0,
                            float* __restrict__ conf0, float* __restrict__ wnorm,
                            unsigned* __restrict__ wsz,
                            short* __restrict__ wfh, short* __restrict__ wfl) {
    const int b = blockIdx.x, l = threadIdx.x;
    if (b >= 64) {
        for (int i = (b - 64) * 64 + l; i < ZERO_WORDS; i += 128) wsz[i] = 0u;
        return;
    }
    {   // frag duty for row b (thread l covers k = l*8 .. l*8+7 -> ks=l>>2, q=l&3)
        int ks = l >> 2, q = l & 3;
        int dst = fragidx(ks, b, q, 0);
        if (b < CN) {
            const float* wp = W + b * DK + l * 8;
            f4 x = *(const f4*)wp, y = *(const f4*)(wp + 4);
            float a8[8] = {x[0], x[1], x[2], x[3], y[0], y[1], y[2], y[3]};
            short8 h, lo2; cvt8(a8, h, lo2);
            *(short8*)(wfh + dst) = h;
            *(short8*)(wfl + dst) = lo2;
        } else {
            short8 z;
            #pragma unroll
            for (int j = 0; j < 8; j++) z[j] = 0;
            *(short8*)(wfh + dst) = z;
            *(short8*)(wfl + dst) = z;
        }
    }
    if (b >= CN) return;

    __shared__ float wrow[DK];
    const int i = b;
    f4 v0 = *(const f4*)(W + i * DK + l * 4);
    f4 v1 = *(const f4*)(W + i * DK + 256 + l * 4);
    *(f4*)(wrow + l * 4) = v0;
    *(f4*)(wrow + 256 + l * 4) = v1;
    float sq = v0[0]*v0[0] + v0[1]*v0[1] + v0[2]*v0[2] + v0[3]*v0[3]
             + v1[0]*v1[0] + v1[1]*v1[1] + v1[2]*v1[2] + v1[3]*v1[3];
    #pragma unroll
    for (int m = 1; m < 64; m <<= 1) sq += __shfl_xor(sq, m);
    if (l == 0) wnorm[i] = sqrtf(sq);
    __syncthreads();

    float dot = -INFINITY;
    int   ai  = 0x7fffffff;
    if (l < CN) {
        const float* wj = W + l * DK;
        float d2 = 0.f;
        for (int d = 0; d < DK; d += 4) {
            f4 a = *(const f4*)(wrow + d);
            f4 b4 = *(const f4*)(wj + d);
            d2 = fmaf(a[0], b4[0], fmaf(a[1], b4[1], fmaf(a[2], b4[2], fmaf(a[3], b4[3], d2))));
        }
        dot = d2 + bias[l];
        ai  = l;
    }
    float mx = dot; int am = ai;
    #pragma unroll
    for (int m = 32; m >= 1; m >>= 1) {
        float o = __shfl_xor(mx, m); int oi = __shfl_xor(am, m);
        if (o > mx || (o == mx && oi < am)) { mx = o; am = oi; }
    }
    float e = 0.f, te = 0.f;
    if (l < CN) { e = expf(dot - mx); te = e * (dot - mx); }
    #pragma unroll
    for (int m = 1; m < 64; m <<= 1) { e += __shfl_xor(e, m); te += __shfl_xor(te, m); }
    if (l == 0) {
        lab0[i]  = am;
        ent0[i]  = logf(e) - te / e;
        conf0[i] = 1.f / e;
    }
}

// ---------------- MFMA split-bf16 GEMM, LDS-staged A ----------------
// Block: 64 rows, 256 threads (4 waves), wave w owns rows w*16..w*16+15, N=64.
// MODE 0: logits -> softmax stats + row norms + dual-view consistency + ent-sum
// MODE 1: out = 20 * dot / max(rnorm, eps)
template <int MODE>
__global__ __launch_bounds__(256) void gemm_kernel(
        const float* __restrict__ feat,
        const short* __restrict__ bfh, const short* __restrict__ bfl,
        const float* __restrict__ bias,
        float* __restrict__ ent, float* __restrict__ pmaxA,
        int* __restrict__ yhat, float* __restrict__ rnorm,
        const float* __restrict__ lraw, const float* __restrict__ laug,
        unsigned* __restrict__ consp, Scalars* sc, float* __restrict__ outp) {
    __shared__ float As[MB * ASTR];  // 33.8 KB; reused as logits buffer in MODE 0 epilogue
    const int t = threadIdx.x;
    const int w = t >> 6, lane = t & 63, m = lane & 15, q = lane >> 4;
    const int rb = blockIdx.x * MB;
    const float* fbase = feat + (size_t)rb * DK;

    f4 acc[4];
    #pragma unroll
    for (int nt = 0; nt < 4; nt++) acc[nt] = (f4){0.f, 0.f, 0.f, 0.f};
    float sq = 0.f;

    const int scol = (t & 31) * 4;   // staging col within 128-float chunk
    const int srow0 = t >> 5;        // 0..7

    for (int kc = 0; kc < 4; kc++) {
        if (kc) __syncthreads();
        // stage 64 rows x 128 floats, fully coalesced (32 lanes = 512 B contiguous)
        #pragma unroll
        for (int r8 = 0; r8 < 8; r8++) {
            int row = r8 * 8 + srow0;
            f4 v = *(const f4*)(fbase + (size_t)row * DK + kc * 128 + scol);
            *(f4*)(&As[row * ASTR + scol]) = v;
        }
        __syncthreads();
        #pragma unroll
        for (int ks = 0; ks < 4; ks++) {
            const float* ap = &As[(w * 16 + m) * ASTR + ks * 32 + q * 8];
            f4 x = *(const f4*)ap;
            f4 y = *(const f4*)(ap + 4);
            float a8[8] = {x[0], x[1], x[2], x[3], y[0], y[1], y[2], y[3]};
            if (MODE == 0) {
                sq += x[0]*x[0] + x[1]*x[1] + x[2]*x[2] + x[3]*x[3]
                    + y[0]*y[0] + y[1]*y[1] + y[2]*y[2] + y[3]*y[3];
            }
            short8 ah, al;
            cvt8(a8, ah, al);
            const int ksg = kc * 4 + ks;
            short8 bh[4], bl[4];
            #pragma unroll
            for (int nt = 0; nt < 4; nt++) {
                int off = ksg * 2048 + nt * 512 + lane * 8;
                bh[nt] = *(const short8*)(bfh + off);
                bl[nt] = *(const short8*)(bfl + off);
            }
            #pragma unroll
            for (int nt = 0; nt < 4; nt++) {
                acc[nt] = __builtin_amdgcn_mfma_f32_16x16x32_bf16(ah, bh[nt], acc[nt], 0, 0, 0);
                acc[nt] = __builtin_amdgcn_mfma_f32_16x16x32_bf16(al, bh[nt], acc[nt], 0, 0, 0);
                acc[nt] = __builtin_amdgcn_mfma_f32_16x16x32_bf16(ah, bl[nt], acc[nt], 0, 0, 0);
            }
        }
    }

    if (MODE == 0) {
        // row norms: lane (m,q) holds disjoint k-slices of row w*16+m
        float s = sq;
        s += __shfl_xor(s, 16);
        s += __shfl_xor(s, 32);
        if (q == 0) rnorm[rb + w * 16 + m] = sqrtf(s);
        __syncthreads();   // done reading As; reuse as logits buffer
        float* L = As;     // 64 x 65
        float bc[4];
        #pragma unroll
        for (int nt = 0; nt < 4; nt++) { int c = nt * 16 + m; bc[nt] = (c < CN) ? bias[c] : 0.f; }
        #pragma unroll
        for (int nt = 0; nt < 4; nt++)
            #pragma unroll
            for (int r = 0; r < 4; r++) {
                int row = w * 16 + q * 4 + r;
                L[row * 65 + nt * 16 + m] = acc[nt][r] + bc[nt];
            }
        __syncthreads();
        if (t < MB) {
            int grow = rb + t;
            const float* Lr = L + t * 65;
            float mx = Lr[0]; int am = 0;
            #pragma unroll 10
            for (int j = 1; j < CN; j++) { float v = Lr[j]; if (v > mx) { mx = v; am = j; } }
            float ssum = 0.f, tt = 0.f;
            for (int j = 0; j < CN; j++) {
                float d = Lr[j] - mx;
                float e = expf(d);
                ssum += e; tt += e * d;
            }
            float ev = logf(ssum) - tt / ssum;
            ent  [grow] = ev;
            pmaxA[grow] = 1.f / ssum;
            yhat [grow] = am;
            // dual-view consistency
            const float* rp  = lraw + (size_t)grow * CN;
            const float* apg = laug + (size_t)grow * CN;
            float m1 = rp[0];  int a1 = 0;
            float m2 = apg[0]; int a2 = 0;
            #pragma unroll 10
            for (int j = 1; j < CN; j++) {
                float v1 = rp[j];  if (v1 > m1) { m1 = v1; a1 = j; }
                float v2 = apg[j]; if (v2 > m2) { m2 = v2; a2 = j; }
            }
            consp[grow] = (a1 == a2) ? 1u : 0u;
            // ent-sum: one atomic per wave (threads 0..63 are wave 0)
            float es = ev;
            #pragma unroll
            for (int mk = 1; mk < 64; mk <<= 1) es += __shfl_xor(es, mk);
            if (t == 0) atomicAdd(&sc->sum_ent, es);
        }
    } else {
        #pragma unroll
        for (int r = 0; r < 4; r++) {
            int grow = rb + w * 16 + q * 4 + r;
            float s = 20.f / fmaxf(rnorm[grow], 1e-12f);
            #pragma unroll
            for (int nt = 0; nt < 4; nt++) {
                int c = nt * 16 + m;
                if (c < CN) outp[(size_t)grow * CN + c] = acc[nt][r] * s;
            }
        }
    }
}

// ---------------- 3-pass radix select (11/11/10 bits) ----------------
__global__ __launch_bounds__(256) void sel1_kernel(const float* __restrict__ ent,
                                                   unsigned* __restrict__ H1, Scalars* sc) {
    __shared__ unsigned h[2048];
    __shared__ unsigned part[256];
    __shared__ int last;
    const int t = threadIdx.x;
    for (int b = t; b < 2048; b += 256) h[b] = 0u;
    __syncthreads();
    const int lo = blockIdx.x * (BN / SELB), hi = lo + (BN / SELB);
    for (int i = lo + t; i < hi; i += 256)
        atomicAdd(&h[fkey(ent[i]) >> 21], 1u);
    __syncthreads();
    for (int b = t; b < 2048; b += 256) if (h[b]) atomicAdd(&H1[b], h[b]);
    __threadfence();
    if (t == 0) last = (atomicAdd(&sc->done1, 1u) == SELB - 1) ? 1 : 0;
    __syncthreads();
    if (!last) return;

    for (int b = t; b < 2048; b += 256) h[b] = atomicAdd(&H1[b], 0u);
    __syncthreads();
    unsigned ps = 0;
    #pragma unroll
    for (int j = 0; j < 8; j++) ps += h[t * 8 + j];
    part[t] = ps;
    __syncthreads();
    if (t == 0) {
        float m = sc->sum_ent / (float)BN;
        sc->mean = m;
        float q = (m >= 0.45f) ? 0.25f : ((m >= 0.38f) ? 0.30f : 0.40f);
        sc->conf_thr = (m >= 0.45f) ? 0.72f : 0.62f;
        float pos = q * (float)(BN - 1);
        float flo = floorf(pos);
        sc->frac = pos - flo;
        int klo = (int)flo;
        int khi = klo + 1; if (khi > BN - 1) khi = BN - 1;
        sc->klo = klo; sc->khi = khi;
        for (int pass = 0; pass < 2; pass++) {
            unsigned k = (pass == 0) ? (unsigned)klo : (unsigned)khi;
            unsigned cum = 0; int c = 0;
            for (; c < 255; c++) { unsigned pc = part[c]; if (cum + pc > k) break; cum += pc; }
            int b = c * 8;
            for (; b < c * 8 + 7; b++) { unsigned hb = h[b]; if (cum + hb > k) break; cum += hb; }
            if (pass == 0) { sc->prefix_lo = (unsigned)b; sc->rank_lo = k - cum; }
            else           { sc->prefix_hi = (unsigned)b; sc->rank_hi = k - cum; }
        }
    }
}

__global__ __launch_bounds__(256) void sel2_kernel(const float* __restrict__ ent,
                                                   unsigned* __restrict__ HLO, unsigned* __restrict__ HHI,
                                                   Scalars* sc) {
    __shared__ unsigned hlo[2048], hhi[2048];
    __shared__ unsigned plo_s[256], phi_s[256];
    __shared__ int last;
    const int t = threadIdx.x;
    const unsigned plo = sc->prefix_lo, phi = sc->prefix_hi;
    for (int b = t; b < 2048; b += 256) { hlo[b] = 0u; hhi[b] = 0u; }
    __syncthreads();
    const int lo = blockIdx.x * (BN / SELB), hi = lo + (BN / SELB);
    for (int i = lo + t; i < hi; i += 256) {
        unsigned u = fkey(ent[i]);
        unsigned d1 = u >> 21, d2 = (u >> 10) & 2047u;
        if (d1 == plo) atomicAdd(&hlo[d2], 1u);
        if (d1 == phi) atomicAdd(&hhi[d2], 1u);
    }
    __syncthreads();
    for (int b = t; b < 2048; b += 256) {
        if (hlo[b]) atomicAdd(&HLO[b], hlo[b]);
        if (hhi[b]) atomicAdd(&HHI[b], hhi[b]);
    }
    __threadfence();
    if (t == 0) last = (atomicAdd(&sc->done2, 1u) == SELB - 1) ? 1 : 0;
    __syncthreads();
    if (!last) return;

    for (int b = t; b < 2048; b += 256) { hlo[b] = atomicAdd(&HLO[b], 0u); hhi[b] = atomicAdd(&HHI[b], 0u); }
    __syncthreads();
    unsigned pl = 0, ph = 0;
    #pragma unroll
    for (int j = 0; j < 8; j++) { pl += hlo[t * 8 + j]; ph += hhi[t * 8 + j]; }
    plo_s[t] = pl; phi_s[t] = ph;
    __syncthreads();
    if (t == 0) {
        {
            unsigned k = sc->rank_lo, cum = 0; int c = 0;
            for (; c < 255; c++) { unsigned pc = plo_s[c]; if (cum + pc > k) break; cum += pc; }
            int b = c * 8;
            for (; b < c * 8 + 7; b++) { unsigned hb = hlo[b]; if (cum + hb > k) break; cum += hb; }
            sc->prefix_lo = (plo << 11) | (unsigned)b; sc->rank_lo = k - cum;
        }
        {
            unsigned k = sc->rank_hi, cum = 0; int c = 0;
            for (; c < 255; c++) { unsigned pc = phi_s[c]; if (cum + pc > k) break; cum += pc; }
            int b = c * 8;
            for (; b < c * 8 + 7; b++) { unsigned hb = hhi[b]; if (cum + hb > k) break; cum += hb; }
            sc->prefix_hi = (phi << 11) | (unsigned)b; sc->rank_hi = k - cum;
        }
    }
}

__global__ __launch_bounds__(256) void sel3_kernel(const float* __restrict__ ent,
                                                   unsigned* __restrict__ HLO, unsigned* __restrict__ HHI,
                                                   Scalars* sc) {
    __shared__ unsigned hlo[1024], hhi[1024];
    __shared__ unsigned plo_s[256], phi_s[256];
    __shared__ int last;
    const int t = threadIdx.x;
    const unsigned plo = sc->prefix_lo, phi = sc->prefix_hi;
    for (int b = t; b < 1024; b += 256) { hlo[b] = 0u; hhi[b] = 0u; }
    __syncthreads();
    const int lo = blockIdx.x * (BN / SELB), hi = lo + (BN / SELB);
    for (int i = lo + t; i < hi; i += 256) {
        unsigned u = fkey(ent[i]);
        unsigned p22 = u >> 10, d3 = u & 1023u;
        if (p22 == plo) atomicAdd(&hlo[d3], 1u);
        if (p22 == phi) atomicAdd(&hhi[d3], 1u);
    }
    __syncthreads();
    for (int b = t; b < 1024; b += 256) {
        if (hlo[b]) atomicAdd(&HLO[b], hlo[b]);
        if (hhi[b]) atomicAdd(&HHI[b], hhi[b]);
    }
    __threadfence();
    if (t == 0) last = (atomicAdd(&sc->done3, 1u) == SELB - 1) ? 1 : 0;
    __syncthreads();
    if (!last) return;

    for (int b = t; b < 1024; b += 256) { hlo[b] = atomicAdd(&HLO[b], 0u); hhi[b] = atomicAdd(&HHI[b], 0u); }
    __syncthreads();
    unsigned pl = 0, ph = 0;
    #pragma unroll
    for (int j = 0; j < 4; j++) { pl += hlo[t * 4 + j]; ph += hhi[t * 4 + j]; }
    plo_s[t] = pl; phi_s[t] = ph;
    __syncthreads();
    if (t == 0) {
        float vlo, vhi;
        {
            unsigned k = sc->rank_lo, cum = 0; int c = 0;
            for (; c < 255; c++) { unsigned pc = plo_s[c]; if (cum + pc > k) break; cum += pc; }
            int b = c * 4;
            for (; b < c * 4 + 3; b++) { unsigned hb = hlo[b]; if (cum + hb > k) break; cum += hb; }
            vlo = funkey((plo << 10) | (unsigned)b);
        }
        {
            unsigned k = sc->rank_hi, cum = 0; int c = 0;
            for (; c < 255; c++) { unsigned pc = phi_s[c]; if (cum + pc > k) break; cum += pc; }
            int b = c * 4;
            for (; b < c * 4 + 3; b++) { unsigned hb = hhi[b]; if (cum + hb > k) break; cum += hb; }
            vhi = funkey((phi << 10) | (unsigned)b);
        }
        sc->thr = vlo * (1.f - sc->frac) + vhi * sc->frac;
    }
}

// ---------------- gating + compaction ----------------
__global__ __launch_bounds__(256) void compact_kernel(
        const float* __restrict__ ent, const float* __restrict__ pmaxA,
        const int* __restrict__ yhat, const unsigned* __restrict__ cons,
        const int* __restrict__ lab0, const float* __restrict__ ent0,
        const float* __restrict__ conf0, Scalars* sc,
        int* le_cls, float* le_ent, float* le_conf, int* le_ord, int* le_src) {
    int i = blockIdx.x * blockDim.x + threadIdx.x;
    if (i < CN) {
        le_cls[i] = lab0[i]; le_ent[i] = ent0[i]; le_conf[i] = conf0[i];
        le_ord[i] = i; le_src[i] = i;
    }
    if (i >= BN) return;
    bool m = (ent[i] <= sc->thr) && (cons[i] != 0u) && (pmaxA[i] >= sc->conf_thr);
    if (m) {
        int pos = (int)atomicAdd(&sc->cnt, 1u);
        int e = CN + pos;
        le_cls[e] = yhat[i]; le_ent[e] = ent[i]; le_conf[e] = pmaxA[i];
        le_ord[e] = CN + i;  le_src[e] = i;
    }
}

// ---------------- class-parallel tail: top-K + centroid + normalize + frag-ize ----------------
__global__ __launch_bounds__(256) void tail2_kernel(
        const Scalars* sc, const int* __restrict__ le_cls,
        const float* __restrict__ le_ent, const float* __restrict__ le_conf,
        const int* __restrict__ le_ord, const int* __restrict__ le_src,
        const float* __restrict__ W, const float* __restrict__ feat,
        const float* __restrict__ wnorm, const float* __restrict__ rnorm,
        short* __restrict__ cfh, short* __restrict__ cfl) {
    const int c = blockIdx.x, t = threadIdx.x;
    if (c >= CN) {   // zero the pad frag rows (50..63)
        for (int idx = t; idx < 512; idx += 256) {
            int ks = idx >> 5, rem = idx & 31, qq = rem >> 3, jj = rem & 7;
            int dst = fragidx(ks, c, qq, jj);
            cfh[dst] = 0; cfl[dst] = 0;
        }
        return;
    }
    __shared__ float sent[CAP];
    __shared__ int   sord[CAP];
    __shared__ float sconf[CAP];
    __shared__ int   ssrc[CAP];
    __shared__ float wk[CAP];
    __shared__ float accv[DK];
    __shared__ float red[4];
    __shared__ int   mc_s;
    if (t == 0) mc_s = 0;
    for (int d = t; d < DK; d += 256) accv[d] = 0.f;
    __syncthreads();
    const int M = CN + (int)sc->cnt;
    for (int e = t; e < M; e += 256) {
        if (le_cls[e] == c) {
            int i = atomicAdd(&mc_s, 1);
            if (i < CAP) { sent[i] = le_ent[e]; sord[i] = le_ord[e]; sconf[i] = le_conf[e]; ssrc[i] = le_src[e]; }
        }
    }
    __syncthreads();
    int mc = min(mc_s, CAP);
    for (int i = t; i < mc; i += 256) {
        float v = sent[i]; int o = sord[i]; int r = 0;
        for (int j = 0; j < mc && r < FILTK; j++)
            if (sent[j] < v || (sent[j] == v && sord[j] < o)) r++;
        wk[i] = (r < FILTK) ? fmaxf(sconf[i], 1e-6f) : 0.f;
    }
    __syncthreads();
    for (int i = 0; i < mc; i++) {
        float wgt = wk[i];
        if (wgt <= 0.f) continue;
        int src = ssrc[i];
        bool warm = sord[i] < CN;
        const float* rowp = warm ? (W + src * DK) : (feat + (size_t)src * DK);
        float nr = warm ? wnorm[src] : rnorm[src];
        float k = wgt / fmaxf(nr, 1e-12f);
        for (int d = t; d < DK; d += 256) accv[d] += k * rowp[d];
    }
    __syncthreads();
    float s = 0.f;
    for (int d = t; d < DK; d += 256) { float v = accv[d]; s = fmaf(v, v, s); }
    #pragma unroll
    for (int mk = 1; mk < 64; mk <<= 1) s += __shfl_xor(s, mk);
    if ((t & 63) == 0) red[t >> 6] = s;
    __syncthreads();
    float inv = 1.f / fmaxf(sqrtf(red[0] + red[1] + red[2] + red[3]), 1e-12f);
    for (int k = t; k < DK; k += 256) {
        float v = accv[k] * inv;
        short hh = bf16h(v);
        short ll = bf16h(v - bf16tof(hh));
        int ks = k >> 5, kk = k & 31, qq = kk >> 3, jj = kk & 7;
        int dst = fragidx(ks, c, qq, jj);
        cfh[dst] = hh; cfl[dst] = ll;
    }
}

// ---------------- launch ----------------
extern "C" void kernel_launch(void* const* d_in, const int* in_sizes, int n_in,
                              void* d_out, int out_size, void* d_ws, size_t ws_size,
                              hipStream_t stream) {
    const float* feat = (const float*)d_in[0];
    const float* lraw = (const float*)d_in[1];
    const float* laug = (const float*)d_in[2];
    const float* W    = (const float*)d_in[3];
    const float* bias = (const float*)d_in[4];
    float* out = (float*)d_out;

    unsigned* wsw    = (unsigned*)d_ws;
    Scalars*  sc     = (Scalars*)(wsw + W_SC);
    unsigned* H1     = wsw + W_H1;
    unsigned* H2LO   = wsw + W_H2LO;
    unsigned* H2HI   = wsw + W_H2HI;
    unsigned* H3LO   = wsw + W_H3LO;
    unsigned* H3HI   = wsw + W_H3HI;
    short*    wfh    = (short*)(wsw + W_WFH);
    short*    wfl    = (short*)(wsw + W_WFL);
    short*    cfh    = (short*)(wsw + W_CFH);
    short*    cfl    = (short*)(wsw + W_CFL);
    float*    ent    = (float*)(wsw + W_ENT);
    float*    pmaxA  = (float*)(wsw + W_PMAX);
    int*      yhat   = (int*)(wsw + W_YHAT);
    unsigned* cons   = wsw + W_CONS;
    float*    rnorm  = (float*)(wsw + W_NORM);
    int*      lab0   = (int*)(wsw + W_LAB0);
    float*    ent0   = (float*)(wsw + W_ENT0);
    float*    conf0  = (float*)(wsw + W_CONF0);
    float*    wnorm  = (float*)(wsw + W_WNORM);
    int*      le_cls = (int*)(wsw + W_LECLS);
    float*    le_ent = (float*)(wsw + W_LEENT);
    float*    le_conf= (float*)(wsw + W_LECONF);
    int*      le_ord = (int*)(wsw + W_LEORD);
    int*      le_src = (int*)(wsw + W_LESRC);

    init_kernel<<<66, 64, 0, stream>>>(W, bias, lab0, ent0, conf0, wnorm, wsw, wfh, wfl);
    gemm_kernel<0><<<BN / MB, 256, 0, stream>>>(feat, wfh, wfl, bias, ent, pmaxA, yhat, rnorm,
                                                lraw, laug, cons, sc, nullptr);
    sel1_kernel<<<SELB, 256, 0, stream>>>(ent, H1, sc);
    sel2_kernel<<<SELB, 256, 0, stream>>>(ent, H2LO, H2HI, sc);
    sel3_kernel<<<SELB, 256, 0, stream>>>(ent, H3LO, H3HI, sc);
    compact_kernel<<<BN / 256, 256, 0, stream>>>(ent, pmaxA, yhat, cons, lab0, ent0, conf0, sc,
                                                 le_cls, le_ent, le_conf, le_ord, le_src);
    tail2_kernel<<<64, 256, 0, stream>>>(sc, le_cls, le_ent, le_conf, le_ord, le_src,
                                         W, feat, wnorm, rnorm, cfh, cfl);
    gemm_kernel<1><<<BN / MB, 256, 0, stream>>>(feat, cfh, cfl, nullptr, nullptr, nullptr, nullptr, rnorm,
                                                nullptr, nullptr, nullptr, sc, out);
}